// Round 13
// baseline (392.996 us; speedup 1.0000x reference)
//
#include <hip/hip_runtime.h>

// GraphGCN forward. Round 12: edge MLP latency fixes — 2048-block grid,
// software-pipelined group loads, split reduce chains. GEMM grid 391.
// Round-11 structure otherwise.
// N=50000 nodes, E=1600000 edges, IN=H=128, EA=16, OUT=10.

#define HD   128
#define EAD  16
#define OUTD 10
#define PCHUNK 4096
#define PBLK 400              // pool partial blocks (8 chunks x 50 in k_head)

typedef short bf16x8 __attribute__((ext_vector_type(8)));
typedef float f32x16 __attribute__((ext_vector_type(16)));

static inline int ceil_div(long long a, long long b){ return (int)((a + b - 1) / b); }

__device__ inline unsigned f2bf(float f) {           // RNE f32 -> bf16
    unsigned u = __float_as_uint(f);
    return (u + 0x7fffu + ((u >> 16) & 1u)) >> 16;
}
__device__ inline float bf_lo(unsigned w) { return __uint_as_float(w << 16); }
__device__ inline float bf_hi(unsigned w) { return __uint_as_float(w & 0xffff0000u); }

__device__ inline unsigned short f2h(float f) {
    _Float16 h = (_Float16)f;
    return __builtin_bit_cast(unsigned short, h);
}
__device__ inline float h2f(unsigned u) {            // low 16 bits = f16
    _Float16 h = __builtin_bit_cast(_Float16, (unsigned short)(u & 0xffffu));
    return (float)h;
}
__device__ inline unsigned cvtpk(float lo, float hi) {   // 2xf32 -> packed bf16
    unsigned r;
    asm volatile("v_cvt_pk_bf16_f32 %0, %1, %2" : "=v"(r) : "v"(lo), "v"(hi));
    return r;
}
__device__ inline unsigned relu_pk(unsigned w) {     // relu on packed 2xbf16
    return w & ~(((w >> 15) & 0x10001u) * 0xFFFFu);
}

// ---------------- edge MLP via swapped MFMA + MFMA reduce --------------------
// C1_t[hid_row][edge_col] = (We1^T @ ea^T)_t + be1 (rank-1 MFMA).
// pre = sum_t mfma(We2-slice-as-A, relu(C1_t)); lane reg0 = pre[edge].
// Software-pipelined group loads; fused dst>>8 histogram.
__global__ __launch_bounds__(256) void k_edge_mlp(
    const float* __restrict__ edge_attr, const int* __restrict__ dst,
    const float* __restrict__ We1, const float* __restrict__ be1,
    const float* __restrict__ We2, const float* __restrict__ be2,
    float* __restrict__ ew, int* __restrict__ batom, int E, int NB)
{
    __shared__ int hist[256];
    const int tid = threadIdx.x;
    hist[tid] = 0;
    __syncthreads();

    const int lane = tid & 63;
    const int half = lane >> 5;
    const int lc   = lane & 31;
    const int wid  = blockIdx.x * 4 + (tid >> 6);
    const int nw   = gridDim.x * 4;
    const int G    = (E + 31) >> 5;

    // wave-invariant fragments
    bf16x8 bfr[4];    // A: We1^T block t -> A[row=hid (lc)][k=attr]
    bf16x8 abias[4];  // A: be1 column (k==0 only)
    bf16x8 bones;     // B: ones row (k==0 only)
    bf16x8 we2A[8];   // A: We2 16-slices, all 32 rows equal
#pragma unroll
    for (int t = 0; t < 4; ++t) {
#pragma unroll
        for (int j = 0; j < 8; ++j) {
            int k = 4 * half + (j & 3) + 8 * (j >> 2);
            bfr[t][j]   = (short)f2bf(We1[k * HD + t * 32 + lc]);
            abias[t][j] = (half == 0 && j == 0) ? (short)f2bf(be1[t * 32 + lc]) : (short)0;
        }
    }
#pragma unroll
    for (int j = 0; j < 8; ++j)
        bones[j] = (half == 0 && j == 0) ? (short)0x3F80 : (short)0;
#pragma unroll
    for (int s = 0; s < 8; ++s)
#pragma unroll
        for (int j = 0; j < 8; ++j) {
            int k = 4 * half + (j & 3) + 8 * (j >> 2);
            we2A[s][j] = (short)f2bf(We2[s * 16 + k]);
        }
    const float be2v = be2[0];

    // ---- software-pipelined loop over 32-edge groups ----
    int g = wid;
    float4 a0, a1;
    int dmine = 0;
    if (g < G) {
        int edge  = (g << 5) + lc;
        int eload = edge < E ? edge : E - 1;
        const float4* rowp = reinterpret_cast<const float4*>(edge_attr + (size_t)eload * EAD);
        a0 = rowp[half];
        a1 = rowp[2 + half];
        dmine = dst[eload];
    }
    for (; g < G; g += nw) {
        int gn = g + nw;
        float4 na0, na1;
        int ndm = 0;
        if (gn < G) {                  // prefetch next group (latency hidden)
            int edge  = (gn << 5) + lc;
            int eload = edge < E ? edge : E - 1;
            const float4* rowp = reinterpret_cast<const float4*>(edge_attr + (size_t)eload * EAD);
            na0 = rowp[half];
            na1 = rowp[2 + half];
            ndm = dst[eload];
        }

        int eb   = g << 5;
        int edge = eb + lc;
        bool owner = (half == 0) && (edge < E);
        if (owner) atomicAdd(&hist[((unsigned)dmine) >> 8], 1);

        union { uint2 u[2]; bf16x8 v; } af;
        af.u[0] = make_uint2(cvtpk(a0.x, a0.y), cvtpk(a0.z, a0.w));
        af.u[1] = make_uint2(cvtpk(a1.x, a1.y), cvtpk(a1.z, a1.w));

        f32x16 pre0, pre1;
#pragma unroll
        for (int i = 0; i < 16; ++i) { pre0[i] = 0.f; pre1[i] = 0.f; }
#pragma unroll
        for (int t = 0; t < 4; ++t) {
            f32x16 acc;
#pragma unroll
            for (int i = 0; i < 16; ++i) acc[i] = 0.f;
            acc = __builtin_amdgcn_mfma_f32_32x32x16_bf16(abias[t], bones, acc, 0, 0, 0);
            acc = __builtin_amdgcn_mfma_f32_32x32x16_bf16(bfr[t], af.v, acc, 0, 0, 0);
            union { uint2 u[2]; bf16x8 v; } plo, phi;
            plo.u[0] = make_uint2(cvtpk(fmaxf(acc[0], 0.f),  fmaxf(acc[1], 0.f)),
                                  cvtpk(fmaxf(acc[2], 0.f),  fmaxf(acc[3], 0.f)));
            plo.u[1] = make_uint2(cvtpk(fmaxf(acc[4], 0.f),  fmaxf(acc[5], 0.f)),
                                  cvtpk(fmaxf(acc[6], 0.f),  fmaxf(acc[7], 0.f)));
            phi.u[0] = make_uint2(cvtpk(fmaxf(acc[8], 0.f),  fmaxf(acc[9], 0.f)),
                                  cvtpk(fmaxf(acc[10], 0.f), fmaxf(acc[11], 0.f)));
            phi.u[1] = make_uint2(cvtpk(fmaxf(acc[12], 0.f), fmaxf(acc[13], 0.f)),
                                  cvtpk(fmaxf(acc[14], 0.f), fmaxf(acc[15], 0.f)));
            // two independent accumulation chains (4-deep each)
            pre0 = __builtin_amdgcn_mfma_f32_32x32x16_bf16(we2A[2*t],     plo.v, pre0, 0, 0, 0);
            pre1 = __builtin_amdgcn_mfma_f32_32x32x16_bf16(we2A[2*t + 1], phi.v, pre1, 0, 0, 0);
        }
        float v  = pre0[0] + pre1[0] + be2v;
        float sp = fmaxf(v, 0.f) + log1pf(expf(-fabsf(v)));
        if (owner) ew[edge] = sp;

        a0 = na0; a1 = na1; dmine = ndm;
    }
    __syncthreads();
    if (tid < NB && hist[tid]) atomicAdd(&batom[tid], hist[tid]);
}

// ---------------- scan bucket counts -> boff (exclusive), bcur copy -----------
__global__ __launch_bounds__(256) void k_bscan(
    const int* __restrict__ batom, int* __restrict__ boff,
    int* __restrict__ bcur, int NB)
{
    __shared__ int sh[256];
    int t = threadIdx.x;
    int v = (t < NB) ? batom[t] : 0;
    sh[t] = v;
    __syncthreads();
    for (int off = 1; off < 256; off <<= 1) {
        int add = (t >= off) ? sh[t - off] : 0;
        __syncthreads();
        sh[t] += add;
        __syncthreads();
    }
    if (t < NB) { boff[t] = sh[t] - v; bcur[t] = sh[t] - v; }
    if (t == NB - 1) boff[NB] = sh[t];
}

// ---------------- partition edges into coarse buckets ----------------
__global__ __launch_bounds__(256) void k_part(
    const int* __restrict__ src, const int* __restrict__ dst,
    const float* __restrict__ ew, int* __restrict__ bcur,
    uint2* __restrict__ bbuf, int E, int NB)
{
    __shared__ int hist[256];
    __shared__ int base[256];
    __shared__ int cur[256];
    int t = threadIdx.x;
    hist[t] = 0; cur[t] = 0;
    __syncthreads();
    int eb = blockIdx.x * PCHUNK;
#pragma unroll
    for (int k = 0; k < PCHUNK / 256; ++k) {
        int e = eb + k * 256 + t;
        if (e < E) atomicAdd(&hist[dst[e] >> 8], 1);
    }
    __syncthreads();
    if (t < NB && hist[t]) base[t] = atomicAdd(&bcur[t], hist[t]);
    __syncthreads();
#pragma unroll
    for (int k = 0; k < PCHUNK / 256; ++k) {
        int e = eb + k * 256 + t;
        if (e >= E) continue;
        int d = dst[e];
        int bkt = d >> 8;
        int pos = base[bkt] + atomicAdd(&cur[bkt], 1);
        bbuf[pos] = make_uint2(((unsigned)src[e] << 16) | f2h(ew[e]),
                               (unsigned)(d & 255));
    }
}

// ---------------- per-bucket counting sort: rp, dis, adj ----------------
__global__ __launch_bounds__(256) void k_bucket(
    const int* __restrict__ boff, const uint2* __restrict__ bbuf,
    int* __restrict__ rp, float* __restrict__ dis,
    unsigned* __restrict__ adj, int N, int E, int NB)
{
    __shared__ int   hcnt[256];
    __shared__ int   hexc[256];
    __shared__ int   cur[256];
    __shared__ float degs[256];
    int b = blockIdx.x;
    int t = threadIdx.x;
    hcnt[t] = 0; cur[t] = 0; degs[t] = 0.f;
    __syncthreads();
    int beg = boff[b], end = boff[b + 1];
    for (int i = beg + t; i < end; i += 256) {
        uint2 ent = bbuf[i];
        int dl = (int)ent.y;
        atomicAdd(&hcnt[dl], 1);
        atomicAdd(&degs[dl], h2f(ent.x));
    }
    __syncthreads();
    {
        int v = hcnt[t];
        hexc[t] = v;
        __syncthreads();
        for (int off = 1; off < 256; off <<= 1) {
            int add = (t >= off) ? hexc[t - off] : 0;
            __syncthreads();
            hexc[t] += add;
            __syncthreads();
        }
        hexc[t] -= v;
    }
    int n = (b << 8) + t;
    if (n < N) {
        rp[n]  = beg + hexc[t];
        dis[n] = rsqrtf(fmaxf(1.0f + degs[t], 1e-12f));
    }
    if (b == NB - 1 && t == 0) rp[N] = E;
    __syncthreads();
    for (int i = beg + t; i < end; i += 256) {
        uint2 ent = bbuf[i];
        int dl = (int)ent.y;
        int pos = beg + hexc[dl] + atomicAdd(&cur[dl], 1);
        adj[pos] = ent.x;
    }
}

// ------- MFMA GEMM: Ybf[row] = bf16( dis[row] * (relu?)X[row] @ W ) ----------
template <bool BF16IN, bool RELU>
__global__ __launch_bounds__(256) void k_gemm(
    const void* __restrict__ Xv, const float* __restrict__ W,
    const float* __restrict__ dis, unsigned short* __restrict__ Ybf, int N)
{
    __shared__ unsigned short Wt[128][132];
    int t = threadIdx.x;
#pragma unroll
    for (int i = 0; i < 64; ++i) {
        int e = i * 256 + t;
        int k = e >> 7, n = e & 127;
        Wt[n][k] = (unsigned short)f2bf(W[e]);
    }
    __syncthreads();

    const int lane = t & 63;
    const int half = lane >> 5;
    const int lc   = lane & 31;
    const int wid  = blockIdx.x * 4 + (t >> 6);
    const int nw   = gridDim.x * 4;
    const int T    = (N + 31) >> 5;

    for (int tile = wid; tile < T; tile += nw) {
        int rbase = tile << 5;
        int arow  = rbase + lc; if (arow >= N) arow = N - 1;

        f32x16 acc[4];
#pragma unroll
        for (int tb = 0; tb < 4; ++tb)
#pragma unroll
            for (int i = 0; i < 16; ++i) acc[tb][i] = 0.f;

#pragma unroll
        for (int kk = 0; kk < 8; ++kk) {
            union { uint2 u[2]; bf16x8 v; } af;
            if (BF16IN) {
                const unsigned short* Xb = (const unsigned short*)Xv;
                const unsigned short* rp = Xb + (size_t)arow * HD + kk * 16 + 4 * half;
                uint2 lo = *reinterpret_cast<const uint2*>(rp);
                uint2 hi = *reinterpret_cast<const uint2*>(rp + 8);
                if (RELU) {
                    lo.x = relu_pk(lo.x); lo.y = relu_pk(lo.y);
                    hi.x = relu_pk(hi.x); hi.y = relu_pk(hi.y);
                }
                af.u[0] = lo; af.u[1] = hi;
            } else {
                const float* Xf = (const float*)Xv;
                const float* rp = Xf + (size_t)arow * HD + kk * 16 + 4 * half;
                float4 lo = *reinterpret_cast<const float4*>(rp);
                float4 hi = *reinterpret_cast<const float4*>(rp + 8);
                af.u[0] = make_uint2(cvtpk(lo.x, lo.y), cvtpk(lo.z, lo.w));
                af.u[1] = make_uint2(cvtpk(hi.x, hi.y), cvtpk(hi.z, hi.w));
            }
#pragma unroll
            for (int tb = 0; tb < 4; ++tb) {
                const unsigned short* wp = &Wt[tb * 32 + lc][kk * 16 + 4 * half];
                union { uint2 u[2]; bf16x8 v; } bf_;
                bf_.u[0] = *reinterpret_cast<const uint2*>(wp);
                bf_.u[1] = *reinterpret_cast<const uint2*>(wp + 8);
                acc[tb] = __builtin_amdgcn_mfma_f32_32x32x16_bf16(af.v, bf_.v, acc[tb], 0, 0, 0);
            }
        }

        float disv = dis[arow];
#pragma unroll
        for (int r = 0; r < 16; ++r) {
            int rofs = (r & 3) + 8 * (r >> 2) + 4 * half;
            int grow = rbase + rofs;
            float d = __shfl(disv, rofs, 32);
            if (grow < N) {
#pragma unroll
                for (int tb = 0; tb < 4; ++tb)
                    Ybf[(size_t)grow * HD + tb * 32 + lc] =
                        (unsigned short)f2bf(acc[tb][r] * d);
            }
        }
    }
}

// --- gather: out[n] = bf16( b + dis[n] * (linbf[n] + sum ew*linbf[src]) ) -----
__global__ __launch_bounds__(256) void k_gather(
    const int* __restrict__ rp, const unsigned* __restrict__ adj,
    const unsigned* __restrict__ linbf, const float* __restrict__ dis,
    const float* __restrict__ b, unsigned short* __restrict__ out, int N)
{
    int n = blockIdx.x * 8 + (threadIdx.x >> 5);
    if (n >= N) return;
    int lane = threadIdx.x & 31;
    uint2 sw = *reinterpret_cast<const uint2*>(linbf + (size_t)n * (HD/2) + lane * 2);
    float4 acc;
    acc.x = bf_lo(sw.x); acc.y = bf_hi(sw.x);
    acc.z = bf_lo(sw.y); acc.w = bf_hi(sw.y);
    int beg = rp[n], end = rp[n + 1];
    for (int i0 = beg; i0 < end; i0 += 32) {
        int m = end - i0; if (m > 32) m = 32;
        unsigned a = 0;
        if (lane < m) a = adj[i0 + lane];
        int j = 0;
        for (; j + 8 <= m; j += 8) {
            unsigned ee[8]; uint2 vv[8];
#pragma unroll
            for (int q = 0; q < 8; ++q) ee[q] = __shfl(a, j + q, 32);
#pragma unroll
            for (int q = 0; q < 8; ++q)
                vv[q] = *reinterpret_cast<const uint2*>(linbf + (size_t)(ee[q] >> 16) * (HD/2) + lane * 2);
#pragma unroll
            for (int q = 0; q < 8; ++q) {
                float wq = h2f(ee[q]);
                acc.x = fmaf(wq, bf_lo(vv[q].x), acc.x);
                acc.y = fmaf(wq, bf_hi(vv[q].x), acc.y);
                acc.z = fmaf(wq, bf_lo(vv[q].y), acc.z);
                acc.w = fmaf(wq, bf_hi(vv[q].y), acc.w);
            }
        }
        for (; j < m; ++j) {
            unsigned e0 = __shfl(a, j, 32);
            uint2 v0 = *reinterpret_cast<const uint2*>(linbf + (size_t)(e0 >> 16) * (HD/2) + lane * 2);
            float w0 = h2f(e0);
            acc.x = fmaf(w0, bf_lo(v0.x), acc.x);
            acc.y = fmaf(w0, bf_hi(v0.x), acc.y);
            acc.z = fmaf(w0, bf_lo(v0.y), acc.z);
            acc.w = fmaf(w0, bf_hi(v0.y), acc.w);
        }
    }
    float dn = dis[n];
    float4 bv = reinterpret_cast<const float4*>(b)[lane];
    unsigned w0 = cvtpk(fmaf(dn, acc.x, bv.x), fmaf(dn, acc.y, bv.y));
    unsigned w1 = cvtpk(fmaf(dn, acc.z, bv.z), fmaf(dn, acc.w, bv.w));
    *reinterpret_cast<uint2*>(out + (size_t)n * HD + lane * 4) = make_uint2(w0, w1);
}

// ---------------- pool partials: 16 rows x 16 chunks per block-iter ----------
__global__ __launch_bounds__(256) void k_pool(
    const unsigned short* __restrict__ h, float* __restrict__ part, int N)
{
    __shared__ float sm[16][128];
    int t  = threadIdx.x;
    int cg = t & 15;              // uint4 chunk (8 bf16) within row
    int rs = t >> 4;              // row slot 0..15
    float acc[8];
#pragma unroll
    for (int i = 0; i < 8; ++i) acc[i] = 0.f;
    for (int r = blockIdx.x * 16 + rs; r < N; r += gridDim.x * 16) {
        uint4 v = *reinterpret_cast<const uint4*>(h + (size_t)r * HD + cg * 8);
        acc[0] += fmaxf(bf_lo(v.x), 0.f);
        acc[1] += fmaxf(bf_hi(v.x), 0.f);
        acc[2] += fmaxf(bf_lo(v.y), 0.f);
        acc[3] += fmaxf(bf_hi(v.y), 0.f);
        acc[4] += fmaxf(bf_lo(v.z), 0.f);
        acc[5] += fmaxf(bf_hi(v.z), 0.f);
        acc[6] += fmaxf(bf_lo(v.w), 0.f);
        acc[7] += fmaxf(bf_hi(v.w), 0.f);
    }
#pragma unroll
    for (int i = 0; i < 8; ++i) sm[rs][cg * 8 + i] = acc[i];
    __syncthreads();
    if (t < 128) {
        float s = 0.f;
#pragma unroll
        for (int k = 0; k < 16; ++k) s += sm[k][t];
        part[blockIdx.x * HD + t] = s;
    }
}

// ---- head: parallel partial-sum (8 chunks x 50) + wave-parallel GEMV --------
__global__ __launch_bounds__(1024) void k_head(
    const float* __restrict__ part, const float* __restrict__ Wh,
    const float* __restrict__ bh, float* __restrict__ out, float invN)
{
    __shared__ float smc[8][128];
    __shared__ float col[HD];
    int t = threadIdx.x;
    {
        int c  = t & 127;             // column
        int ch = t >> 7;              // chunk 0..7 (50 partials each)
        float s0 = 0.f, s1 = 0.f;
        int k0 = ch * 50;
#pragma unroll
        for (int k = 0; k < 50; k += 2) {
            s0 += part[(k0 + k)     * HD + c];
            s1 += part[(k0 + k + 1) * HD + c];
        }
        smc[ch][c] = s0 + s1;
    }
    __syncthreads();
    if (t < 128) {
        float s = 0.f;
#pragma unroll
        for (int k = 0; k < 8; ++k) s += smc[k][t];
        col[t] = s * invN;
    }
    __syncthreads();
    {
        int o = t >> 6;               // output index (only o<OUTD active)
        int l = t & 63;
        if (o < OUTD) {
            float acc = col[l] * Wh[l * OUTD + o]
                      + col[l + 64] * Wh[(l + 64) * OUTD + o];
#pragma unroll
            for (int off = 1; off < 64; off <<= 1)
                acc += __shfl_xor(acc, off, 64);
            if (l == 0) out[o] = acc + bh[o];
        }
    }
}

extern "C" void kernel_launch(void* const* d_in, const int* in_sizes, int n_in,
                              void* d_out, int out_size, void* d_ws, size_t ws_size,
                              hipStream_t stream)
{
    const float* x         = (const float*)d_in[0];
    const int*   ei        = (const int*)  d_in[1];
    const float* edge_attr = (const float*)d_in[2];
    const float* We1       = (const float*)d_in[3];
    const float* be1       = (const float*)d_in[4];
    const float* We2       = (const float*)d_in[5];
    const float* be2       = (const float*)d_in[6];
    const float* W1        = (const float*)d_in[7];
    const float* b1        = (const float*)d_in[8];
    const float* W2        = (const float*)d_in[9];
    const float* b2        = (const float*)d_in[10];
    const float* W3        = (const float*)d_in[11];
    const float* b3        = (const float*)d_in[12];
    const float* Wh        = (const float*)d_in[13];
    const float* bh        = (const float*)d_in[14];

    const int N = in_sizes[0] / HD;
    const int E = in_sizes[2] / EAD;
    const int NB = (N + 255) >> 8;
    const int* srcp = ei;
    const int* dstp = ei + E;

    // workspace partition
    char* w = (char*)d_ws;
    float*          ew   = (float*)w;          w += (size_t)E * sizeof(float);
    float*          dis  = (float*)w;          w += (size_t)N * sizeof(float);
    unsigned short* Bbf  = (unsigned short*)w; w += (size_t)N * HD * sizeof(unsigned short);
    unsigned*       Abf  = (unsigned*)w;       w += (size_t)N * (HD/2) * sizeof(unsigned);
    float*          part = (float*)w;          w += (size_t)PBLK * HD * sizeof(float);
    int*            rp   = (int*)w;            w += (size_t)(N + 2) * sizeof(int);
    int*            batom= (int*)w;            w += 256 * sizeof(int);
    int*            boff = (int*)w;            w += 260 * sizeof(int);
    int*            bcur = (int*)w;            w += 256 * sizeof(int);
    w = (char*)(((uintptr_t)w + 15) & ~(uintptr_t)15);
    uint2*          bbuf = (uint2*)w;          w += (size_t)E * sizeof(uint2);
    unsigned*       adj  = (unsigned*)w;       w += (size_t)E * sizeof(unsigned);

    const int gGe   = ceil_div(N, 8);
    const int gPart = ceil_div(E, PCHUNK);
    const int T     = (N + 31) >> 5;           // GEMM row tiles
    const int gGemm = ceil_div(T, 4);          // 1 tile per wave

    // batom = 0, then edge MLP (swapped MFMA, pipelined, fused bucket count)
    hipMemsetAsync(batom, 0, 256 * sizeof(int), stream);
    k_edge_mlp<<<2048, 256, 0, stream>>>(edge_attr, dstp, We1, be1, We2, be2,
                                         ew, batom, E, NB);

    // CSR build: scan -> partition -> per-bucket sort
    k_bscan <<<1, 256, 0, stream>>>(batom, boff, bcur, NB);
    k_part  <<<gPart, 256, 0, stream>>>(srcp, dstp, ew, bcur, bbuf, E, NB);
    k_bucket<<<NB, 256, 0, stream>>>(boff, bbuf, rp, dis, adj, N, E, NB);

    // layer 1 (x is f32, no relu)
    k_gemm<false, false><<<gGemm, 256, 0, stream>>>(x, W1, dis, (unsigned short*)Abf, N);
    k_gather<<<gGe, 256, 0, stream>>>(rp, adj, Abf, dis, b1, Bbf, N);
    // layer 2 (bf16 input, relu)
    k_gemm<true, true><<<gGemm, 256, 0, stream>>>(Bbf, W2, dis, (unsigned short*)Abf, N);
    k_gather<<<gGe, 256, 0, stream>>>(rp, adj, Abf, dis, b2, Bbf, N);
    // layer 3
    k_gemm<true, true><<<gGemm, 256, 0, stream>>>(Bbf, W3, dis, (unsigned short*)Abf, N);
    k_gather<<<gGe, 256, 0, stream>>>(rp, adj, Abf, dis, b3, Bbf, N);

    // pool + head
    k_pool<<<PBLK, 256, 0, stream>>>(Bbf, part, N);
    k_head<<<1, 1024, 0, stream>>>(part, Wh, bh, (float*)d_out, 1.0f / (float)N);
}

// Round 14
// 373.831 us; speedup vs baseline: 1.0513x; 1.0513x over previous
//
#include <hip/hip_runtime.h>

// GraphGCN forward. Round 13: round-11 structure restored (1024-blk edge MLP,
// gemm grid 196) + fast softplus via v_exp_f32/v_log_f32 (the libcall
// expf/log1pf was ~70% of edge MLP's VALU mass).
// N=50000 nodes, E=1600000 edges, IN=H=128, EA=16, OUT=10.

#define HD   128
#define EAD  16
#define OUTD 10
#define PCHUNK 4096
#define PBLK 400              // pool partial blocks (8 chunks x 50 in k_head)

typedef short bf16x8 __attribute__((ext_vector_type(8)));
typedef float f32x16 __attribute__((ext_vector_type(16)));

static inline int ceil_div(long long a, long long b){ return (int)((a + b - 1) / b); }

__device__ inline unsigned f2bf(float f) {           // RNE f32 -> bf16
    unsigned u = __float_as_uint(f);
    return (u + 0x7fffu + ((u >> 16) & 1u)) >> 16;
}
__device__ inline float bf_lo(unsigned w) { return __uint_as_float(w << 16); }
__device__ inline float bf_hi(unsigned w) { return __uint_as_float(w & 0xffff0000u); }

__device__ inline unsigned short f2h(float f) {
    _Float16 h = (_Float16)f;
    return __builtin_bit_cast(unsigned short, h);
}
__device__ inline float h2f(unsigned u) {            // low 16 bits = f16
    _Float16 h = __builtin_bit_cast(_Float16, (unsigned short)(u & 0xffffu));
    return (float)h;
}
__device__ inline unsigned cvtpk(float lo, float hi) {   // 2xf32 -> packed bf16
    unsigned r;
    asm volatile("v_cvt_pk_bf16_f32 %0, %1, %2" : "=v"(r) : "v"(lo), "v"(hi));
    return r;
}
__device__ inline unsigned relu_pk(unsigned w) {     // relu on packed 2xbf16
    return w & ~(((w >> 15) & 0x10001u) * 0xFFFFu);
}
// fast softplus: max(v,0) + ln2 * log2(1 + 2^(-|v|*log2e)) — raw HW trans ops
__device__ inline float softplus_fast(float v) {
    float t = __builtin_amdgcn_exp2f(-fabsf(v) * 1.44269504088896f);
    return fmaxf(v, 0.f) + 0.693147180559945f * __builtin_amdgcn_logf(1.0f + t);
}

// ---------------- edge MLP via swapped MFMA + MFMA reduce --------------------
// C1_t[hid_row][edge_col] = (We1^T @ ea^T)_t + be1 (rank-1 MFMA).
// pre = sum_t mfma(We2-slice-as-A, relu(C1_t)); lane reg0 = pre[edge].
// Fused: LDS histogram of dst>>8 -> batom.
__global__ __launch_bounds__(256) void k_edge_mlp(
    const float* __restrict__ edge_attr, const int* __restrict__ dst,
    const float* __restrict__ We1, const float* __restrict__ be1,
    const float* __restrict__ We2, const float* __restrict__ be2,
    float* __restrict__ ew, int* __restrict__ batom, int E, int NB)
{
    __shared__ int hist[256];
    const int tid = threadIdx.x;
    hist[tid] = 0;
    __syncthreads();

    const int lane = tid & 63;
    const int half = lane >> 5;
    const int lc   = lane & 31;
    const int wid  = blockIdx.x * 4 + (tid >> 6);
    const int nw   = gridDim.x * 4;
    const int G    = (E + 31) >> 5;

    // wave-invariant fragments
    bf16x8 bfr[4];    // A: We1^T block t -> A[row=hid (lc)][k=attr]
    bf16x8 abias[4];  // A: be1 column (k==0 only)
    bf16x8 bones;     // B: ones row (k==0 only)
    bf16x8 we2A[8];   // A: We2 16-slices, all 32 rows equal
#pragma unroll
    for (int t = 0; t < 4; ++t) {
#pragma unroll
        for (int j = 0; j < 8; ++j) {
            int k = 4 * half + (j & 3) + 8 * (j >> 2);
            bfr[t][j]   = (short)f2bf(We1[k * HD + t * 32 + lc]);
            abias[t][j] = (half == 0 && j == 0) ? (short)f2bf(be1[t * 32 + lc]) : (short)0;
        }
    }
#pragma unroll
    for (int j = 0; j < 8; ++j)
        bones[j] = (half == 0 && j == 0) ? (short)0x3F80 : (short)0;
#pragma unroll
    for (int s = 0; s < 8; ++s)
#pragma unroll
        for (int j = 0; j < 8; ++j) {
            int k = 4 * half + (j & 3) + 8 * (j >> 2);
            we2A[s][j] = (short)f2bf(We2[s * 16 + k]);
        }
    const float be2v = be2[0];

    for (int g = wid; g < G; g += nw) {
        int eb = g << 5;
        int edge = eb + lc;
        int eload = edge < E ? edge : E - 1;
        bool owner = (half == 0) && (edge < E);
        if (owner) atomicAdd(&hist[((unsigned)dst[edge]) >> 8], 1);

        // B fragment: ea^T — lane col = edge, k = 4*half + {0..3, 8..11}
        const float4* rowp = reinterpret_cast<const float4*>(edge_attr + (size_t)eload * EAD);
        float4 a0 = rowp[half];
        float4 a1 = rowp[2 + half];
        union { uint2 u[2]; bf16x8 v; } af;
        af.u[0] = make_uint2(cvtpk(a0.x, a0.y), cvtpk(a0.z, a0.w));
        af.u[1] = make_uint2(cvtpk(a1.x, a1.y), cvtpk(a1.z, a1.w));

        f32x16 pre;
#pragma unroll
        for (int i = 0; i < 16; ++i) pre[i] = 0.f;
#pragma unroll
        for (int t = 0; t < 4; ++t) {
            f32x16 acc;
#pragma unroll
            for (int i = 0; i < 16; ++i) acc[i] = 0.f;
            acc = __builtin_amdgcn_mfma_f32_32x32x16_bf16(abias[t], bones, acc, 0, 0, 0);
            acc = __builtin_amdgcn_mfma_f32_32x32x16_bf16(bfr[t], af.v, acc, 0, 0, 0);
            // relu + pack: C regs r=0..7 -> B-frag rows 0..15; r=8..15 -> rows 16..31
            union { uint2 u[2]; bf16x8 v; } plo, phi;
            plo.u[0] = make_uint2(cvtpk(fmaxf(acc[0], 0.f),  fmaxf(acc[1], 0.f)),
                                  cvtpk(fmaxf(acc[2], 0.f),  fmaxf(acc[3], 0.f)));
            plo.u[1] = make_uint2(cvtpk(fmaxf(acc[4], 0.f),  fmaxf(acc[5], 0.f)),
                                  cvtpk(fmaxf(acc[6], 0.f),  fmaxf(acc[7], 0.f)));
            phi.u[0] = make_uint2(cvtpk(fmaxf(acc[8], 0.f),  fmaxf(acc[9], 0.f)),
                                  cvtpk(fmaxf(acc[10], 0.f), fmaxf(acc[11], 0.f)));
            phi.u[1] = make_uint2(cvtpk(fmaxf(acc[12], 0.f), fmaxf(acc[13], 0.f)),
                                  cvtpk(fmaxf(acc[14], 0.f), fmaxf(acc[15], 0.f)));
            pre = __builtin_amdgcn_mfma_f32_32x32x16_bf16(we2A[2*t],     plo.v, pre, 0, 0, 0);
            pre = __builtin_amdgcn_mfma_f32_32x32x16_bf16(we2A[2*t + 1], phi.v, pre, 0, 0, 0);
        }
        // all C2 rows identical -> every lane's reg0 = pre[edge = eb + lc]
        float v  = pre[0] + be2v;
        float sp = softplus_fast(v);
        if (owner) ew[edge] = sp;
    }
    __syncthreads();
    if (tid < NB && hist[tid]) atomicAdd(&batom[tid], hist[tid]);
}

// ---------------- scan bucket counts -> boff (exclusive), bcur copy -----------
__global__ __launch_bounds__(256) void k_bscan(
    const int* __restrict__ batom, int* __restrict__ boff,
    int* __restrict__ bcur, int NB)
{
    __shared__ int sh[256];
    int t = threadIdx.x;
    int v = (t < NB) ? batom[t] : 0;
    sh[t] = v;
    __syncthreads();
    for (int off = 1; off < 256; off <<= 1) {
        int add = (t >= off) ? sh[t - off] : 0;
        __syncthreads();
        sh[t] += add;
        __syncthreads();
    }
    if (t < NB) { boff[t] = sh[t] - v; bcur[t] = sh[t] - v; }
    if (t == NB - 1) boff[NB] = sh[t];
}

// ---------------- partition edges into coarse buckets ----------------
__global__ __launch_bounds__(256) void k_part(
    const int* __restrict__ src, const int* __restrict__ dst,
    const float* __restrict__ ew, int* __restrict__ bcur,
    uint2* __restrict__ bbuf, int E, int NB)
{
    __shared__ int hist[256];
    __shared__ int base[256];
    __shared__ int cur[256];
    int t = threadIdx.x;
    hist[t] = 0; cur[t] = 0;
    __syncthreads();
    int eb = blockIdx.x * PCHUNK;
#pragma unroll
    for (int k = 0; k < PCHUNK / 256; ++k) {
        int e = eb + k * 256 + t;
        if (e < E) atomicAdd(&hist[dst[e] >> 8], 1);
    }
    __syncthreads();
    if (t < NB && hist[t]) base[t] = atomicAdd(&bcur[t], hist[t]);
    __syncthreads();
#pragma unroll
    for (int k = 0; k < PCHUNK / 256; ++k) {
        int e = eb + k * 256 + t;
        if (e >= E) continue;
        int d = dst[e];
        int bkt = d >> 8;
        int pos = base[bkt] + atomicAdd(&cur[bkt], 1);
        bbuf[pos] = make_uint2(((unsigned)src[e] << 16) | f2h(ew[e]),
                               (unsigned)(d & 255));
    }
}

// ---------------- per-bucket counting sort: rp, dis, adj ----------------
__global__ __launch_bounds__(256) void k_bucket(
    const int* __restrict__ boff, const uint2* __restrict__ bbuf,
    int* __restrict__ rp, float* __restrict__ dis,
    unsigned* __restrict__ adj, int N, int E, int NB)
{
    __shared__ int   hcnt[256];
    __shared__ int   hexc[256];
    __shared__ int   cur[256];
    __shared__ float degs[256];
    int b = blockIdx.x;
    int t = threadIdx.x;
    hcnt[t] = 0; cur[t] = 0; degs[t] = 0.f;
    __syncthreads();
    int beg = boff[b], end = boff[b + 1];
    for (int i = beg + t; i < end; i += 256) {
        uint2 ent = bbuf[i];
        int dl = (int)ent.y;
        atomicAdd(&hcnt[dl], 1);
        atomicAdd(&degs[dl], h2f(ent.x));
    }
    __syncthreads();
    {
        int v = hcnt[t];
        hexc[t] = v;
        __syncthreads();
        for (int off = 1; off < 256; off <<= 1) {
            int add = (t >= off) ? hexc[t - off] : 0;
            __syncthreads();
            hexc[t] += add;
            __syncthreads();
        }
        hexc[t] -= v;
    }
    int n = (b << 8) + t;
    if (n < N) {
        rp[n]  = beg + hexc[t];
        dis[n] = rsqrtf(fmaxf(1.0f + degs[t], 1e-12f));
    }
    if (b == NB - 1 && t == 0) rp[N] = E;
    __syncthreads();
    for (int i = beg + t; i < end; i += 256) {
        uint2 ent = bbuf[i];
        int dl = (int)ent.y;
        int pos = beg + hexc[dl] + atomicAdd(&cur[dl], 1);
        adj[pos] = ent.x;
    }
}

// ------- MFMA GEMM: Ybf[row] = bf16( dis[row] * (relu?)X[row] @ W ) ----------
template <bool BF16IN, bool RELU>
__global__ __launch_bounds__(256) void k_gemm(
    const void* __restrict__ Xv, const float* __restrict__ W,
    const float* __restrict__ dis, unsigned short* __restrict__ Ybf, int N)
{
    __shared__ unsigned short Wt[128][132];
    int t = threadIdx.x;
#pragma unroll
    for (int i = 0; i < 64; ++i) {
        int e = i * 256 + t;
        int k = e >> 7, n = e & 127;
        Wt[n][k] = (unsigned short)f2bf(W[e]);
    }
    __syncthreads();

    const int lane = t & 63;
    const int half = lane >> 5;
    const int lc   = lane & 31;
    const int wid  = blockIdx.x * 4 + (t >> 6);
    const int nw   = gridDim.x * 4;
    const int T    = (N + 31) >> 5;

    for (int tile = wid; tile < T; tile += nw) {
        int rbase = tile << 5;
        int arow  = rbase + lc; if (arow >= N) arow = N - 1;

        f32x16 acc[4];
#pragma unroll
        for (int tb = 0; tb < 4; ++tb)
#pragma unroll
            for (int i = 0; i < 16; ++i) acc[tb][i] = 0.f;

#pragma unroll
        for (int kk = 0; kk < 8; ++kk) {
            union { uint2 u[2]; bf16x8 v; } af;
            if (BF16IN) {
                const unsigned short* Xb = (const unsigned short*)Xv;
                const unsigned short* rp = Xb + (size_t)arow * HD + kk * 16 + 4 * half;
                uint2 lo = *reinterpret_cast<const uint2*>(rp);
                uint2 hi = *reinterpret_cast<const uint2*>(rp + 8);
                if (RELU) {
                    lo.x = relu_pk(lo.x); lo.y = relu_pk(lo.y);
                    hi.x = relu_pk(hi.x); hi.y = relu_pk(hi.y);
                }
                af.u[0] = lo; af.u[1] = hi;
            } else {
                const float* Xf = (const float*)Xv;
                const float* rp = Xf + (size_t)arow * HD + kk * 16 + 4 * half;
                float4 lo = *reinterpret_cast<const float4*>(rp);
                float4 hi = *reinterpret_cast<const float4*>(rp + 8);
                af.u[0] = make_uint2(cvtpk(lo.x, lo.y), cvtpk(lo.z, lo.w));
                af.u[1] = make_uint2(cvtpk(hi.x, hi.y), cvtpk(hi.z, hi.w));
            }
#pragma unroll
            for (int tb = 0; tb < 4; ++tb) {
                const unsigned short* wp = &Wt[tb * 32 + lc][kk * 16 + 4 * half];
                union { uint2 u[2]; bf16x8 v; } bf_;
                bf_.u[0] = *reinterpret_cast<const uint2*>(wp);
                bf_.u[1] = *reinterpret_cast<const uint2*>(wp + 8);
                acc[tb] = __builtin_amdgcn_mfma_f32_32x32x16_bf16(af.v, bf_.v, acc[tb], 0, 0, 0);
            }
        }

        float disv = dis[arow];
#pragma unroll
        for (int r = 0; r < 16; ++r) {
            int rofs = (r & 3) + 8 * (r >> 2) + 4 * half;
            int grow = rbase + rofs;
            float d = __shfl(disv, rofs, 32);
            if (grow < N) {
#pragma unroll
                for (int tb = 0; tb < 4; ++tb)
                    Ybf[(size_t)grow * HD + tb * 32 + lc] =
                        (unsigned short)f2bf(acc[tb][r] * d);
            }
        }
    }
}

// --- gather: out[n] = bf16( b + dis[n] * (linbf[n] + sum ew*linbf[src]) ) -----
__global__ __launch_bounds__(256) void k_gather(
    const int* __restrict__ rp, const unsigned* __restrict__ adj,
    const unsigned* __restrict__ linbf, const float* __restrict__ dis,
    const float* __restrict__ b, unsigned short* __restrict__ out, int N)
{
    int n = blockIdx.x * 8 + (threadIdx.x >> 5);
    if (n >= N) return;
    int lane = threadIdx.x & 31;
    uint2 sw = *reinterpret_cast<const uint2*>(linbf + (size_t)n * (HD/2) + lane * 2);
    float4 acc;
    acc.x = bf_lo(sw.x); acc.y = bf_hi(sw.x);
    acc.z = bf_lo(sw.y); acc.w = bf_hi(sw.y);
    int beg = rp[n], end = rp[n + 1];
    for (int i0 = beg; i0 < end; i0 += 32) {
        int m = end - i0; if (m > 32) m = 32;
        unsigned a = 0;
        if (lane < m) a = adj[i0 + lane];
        int j = 0;
        for (; j + 8 <= m; j += 8) {
            unsigned ee[8]; uint2 vv[8];
#pragma unroll
            for (int q = 0; q < 8; ++q) ee[q] = __shfl(a, j + q, 32);
#pragma unroll
            for (int q = 0; q < 8; ++q)
                vv[q] = *reinterpret_cast<const uint2*>(linbf + (size_t)(ee[q] >> 16) * (HD/2) + lane * 2);
#pragma unroll
            for (int q = 0; q < 8; ++q) {
                float wq = h2f(ee[q]);
                acc.x = fmaf(wq, bf_lo(vv[q].x), acc.x);
                acc.y = fmaf(wq, bf_hi(vv[q].x), acc.y);
                acc.z = fmaf(wq, bf_lo(vv[q].y), acc.z);
                acc.w = fmaf(wq, bf_hi(vv[q].y), acc.w);
            }
        }
        for (; j < m; ++j) {
            unsigned e0 = __shfl(a, j, 32);
            uint2 v0 = *reinterpret_cast<const uint2*>(linbf + (size_t)(e0 >> 16) * (HD/2) + lane * 2);
            float w0 = h2f(e0);
            acc.x = fmaf(w0, bf_lo(v0.x), acc.x);
            acc.y = fmaf(w0, bf_hi(v0.x), acc.y);
            acc.z = fmaf(w0, bf_lo(v0.y), acc.z);
            acc.w = fmaf(w0, bf_hi(v0.y), acc.w);
        }
    }
    float dn = dis[n];
    float4 bv = reinterpret_cast<const float4*>(b)[lane];
    unsigned w0 = cvtpk(fmaf(dn, acc.x, bv.x), fmaf(dn, acc.y, bv.y));
    unsigned w1 = cvtpk(fmaf(dn, acc.z, bv.z), fmaf(dn, acc.w, bv.w));
    *reinterpret_cast<uint2*>(out + (size_t)n * HD + lane * 4) = make_uint2(w0, w1);
}

// ---------------- pool partials: 16 rows x 16 chunks per block-iter ----------
__global__ __launch_bounds__(256) void k_pool(
    const unsigned short* __restrict__ h, float* __restrict__ part, int N)
{
    __shared__ float sm[16][128];
    int t  = threadIdx.x;
    int cg = t & 15;              // uint4 chunk (8 bf16) within row
    int rs = t >> 4;              // row slot 0..15
    float acc[8];
#pragma unroll
    for (int i = 0; i < 8; ++i) acc[i] = 0.f;
    for (int r = blockIdx.x * 16 + rs; r < N; r += gridDim.x * 16) {
        uint4 v = *reinterpret_cast<const uint4*>(h + (size_t)r * HD + cg * 8);
        acc[0] += fmaxf(bf_lo(v.x), 0.f);
        acc[1] += fmaxf(bf_hi(v.x), 0.f);
        acc[2] += fmaxf(bf_lo(v.y), 0.f);
        acc[3] += fmaxf(bf_hi(v.y), 0.f);
        acc[4] += fmaxf(bf_lo(v.z), 0.f);
        acc[5] += fmaxf(bf_hi(v.z), 0.f);
        acc[6] += fmaxf(bf_lo(v.w), 0.f);
        acc[7] += fmaxf(bf_hi(v.w), 0.f);
    }
#pragma unroll
    for (int i = 0; i < 8; ++i) sm[rs][cg * 8 + i] = acc[i];
    __syncthreads();
    if (t < 128) {
        float s = 0.f;
#pragma unroll
        for (int k = 0; k < 16; ++k) s += sm[k][t];
        part[blockIdx.x * HD + t] = s;
    }
}

// ---- head: parallel partial-sum (8 chunks x 50) + wave-parallel GEMV --------
__global__ __launch_bounds__(1024) void k_head(
    const float* __restrict__ part, const float* __restrict__ Wh,
    const float* __restrict__ bh, float* __restrict__ out, float invN)
{
    __shared__ float smc[8][128];
    __shared__ float col[HD];
    int t = threadIdx.x;
    {
        int c  = t & 127;             // column
        int ch = t >> 7;              // chunk 0..7 (50 partials each)
        float s0 = 0.f, s1 = 0.f;
        int k0 = ch * 50;
#pragma unroll
        for (int k = 0; k < 50; k += 2) {
            s0 += part[(k0 + k)     * HD + c];
            s1 += part[(k0 + k + 1) * HD + c];
        }
        smc[ch][c] = s0 + s1;
    }
    __syncthreads();
    if (t < 128) {
        float s = 0.f;
#pragma unroll
        for (int k = 0; k < 8; ++k) s += smc[k][t];
        col[t] = s * invN;
    }
    __syncthreads();
    {
        int o = t >> 6;               // output index (only o<OUTD active)
        int l = t & 63;
        if (o < OUTD) {
            float acc = col[l] * Wh[l * OUTD + o]
                      + col[l + 64] * Wh[(l + 64) * OUTD + o];
#pragma unroll
            for (int off = 1; off < 64; off <<= 1)
                acc += __shfl_xor(acc, off, 64);
            if (l == 0) out[o] = acc + bh[o];
        }
    }
}

extern "C" void kernel_launch(void* const* d_in, const int* in_sizes, int n_in,
                              void* d_out, int out_size, void* d_ws, size_t ws_size,
                              hipStream_t stream)
{
    const float* x         = (const float*)d_in[0];
    const int*   ei        = (const int*)  d_in[1];
    const float* edge_attr = (const float*)d_in[2];
    const float* We1       = (const float*)d_in[3];
    const float* be1       = (const float*)d_in[4];
    const float* We2       = (const float*)d_in[5];
    const float* be2       = (const float*)d_in[6];
    const float* W1        = (const float*)d_in[7];
    const float* b1        = (const float*)d_in[8];
    const float* W2        = (const float*)d_in[9];
    const float* b2        = (const float*)d_in[10];
    const float* W3        = (const float*)d_in[11];
    const float* b3        = (const float*)d_in[12];
    const float* Wh        = (const float*)d_in[13];
    const float* bh        = (const float*)d_in[14];

    const int N = in_sizes[0] / HD;
    const int E = in_sizes[2] / EAD;
    const int NB = (N + 255) >> 8;
    const int* srcp = ei;
    const int* dstp = ei + E;

    // workspace partition
    char* w = (char*)d_ws;
    float*          ew   = (float*)w;          w += (size_t)E * sizeof(float);
    float*          dis  = (float*)w;          w += (size_t)N * sizeof(float);
    unsigned short* Bbf  = (unsigned short*)w; w += (size_t)N * HD * sizeof(unsigned short);
    unsigned*       Abf  = (unsigned*)w;       w += (size_t)N * (HD/2) * sizeof(unsigned);
    float*          part = (float*)w;          w += (size_t)PBLK * HD * sizeof(float);
    int*            rp   = (int*)w;            w += (size_t)(N + 2) * sizeof(int);
    int*            batom= (int*)w;            w += 256 * sizeof(int);
    int*            boff = (int*)w;            w += 260 * sizeof(int);
    int*            bcur = (int*)w;            w += 256 * sizeof(int);
    w = (char*)(((uintptr_t)w + 15) & ~(uintptr_t)15);
    uint2*          bbuf = (uint2*)w;          w += (size_t)E * sizeof(uint2);
    unsigned*       adj  = (unsigned*)w;       w += (size_t)E * sizeof(unsigned);

    const int gGe   = ceil_div(N, 8);
    const int gPart = ceil_div(E, PCHUNK);
    const int gGemm = 196;

    // batom = 0, then edge MLP (swapped MFMA, fused bucket count)
    hipMemsetAsync(batom, 0, 256 * sizeof(int), stream);
    k_edge_mlp<<<1024, 256, 0, stream>>>(edge_attr, dstp, We1, be1, We2, be2,
                                         ew, batom, E, NB);

    // CSR build: scan -> partition -> per-bucket sort
    k_bscan <<<1, 256, 0, stream>>>(batom, boff, bcur, NB);
    k_part  <<<gPart, 256, 0, stream>>>(srcp, dstp, ew, bcur, bbuf, E, NB);
    k_bucket<<<NB, 256, 0, stream>>>(boff, bbuf, rp, dis, adj, N, E, NB);

    // layer 1 (x is f32, no relu)
    k_gemm<false, false><<<gGemm, 256, 0, stream>>>(x, W1, dis, (unsigned short*)Abf, N);
    k_gather<<<gGe, 256, 0, stream>>>(rp, adj, Abf, dis, b1, Bbf, N);
    // layer 2 (bf16 input, relu)
    k_gemm<true, true><<<gGemm, 256, 0, stream>>>(Bbf, W2, dis, (unsigned short*)Abf, N);
    k_gather<<<gGe, 256, 0, stream>>>(rp, adj, Abf, dis, b2, Bbf, N);
    // layer 3
    k_gemm<true, true><<<gGemm, 256, 0, stream>>>(Bbf, W3, dis, (unsigned short*)Abf, N);
    k_gather<<<gGe, 256, 0, stream>>>(rp, adj, Abf, dis, b3, Bbf, N);

    // pool + head
    k_pool<<<PBLK, 256, 0, stream>>>(Bbf, part, N);
    k_head<<<1, 1024, 0, stream>>>(part, Wh, bh, (float*)d_out, 1.0f / (float)N);
}

// Round 15
// 372.331 us; speedup vs baseline: 1.0555x; 1.0040x over previous
//
#include <hip/hip_runtime.h>

// GraphGCN forward. Round 14: edge MLP processes 2 groups/iter (in-wave ILP,
// contiguous 4KB loads); gather inner loop unrolled x16. Round-13 otherwise.
// N=50000 nodes, E=1600000 edges, IN=H=128, EA=16, OUT=10.

#define HD   128
#define EAD  16
#define OUTD 10
#define PCHUNK 4096
#define PBLK 400              // pool partial blocks (8 chunks x 50 in k_head)

typedef short bf16x8 __attribute__((ext_vector_type(8)));
typedef float f32x16 __attribute__((ext_vector_type(16)));

static inline int ceil_div(long long a, long long b){ return (int)((a + b - 1) / b); }

__device__ inline unsigned f2bf(float f) {           // RNE f32 -> bf16
    unsigned u = __float_as_uint(f);
    return (u + 0x7fffu + ((u >> 16) & 1u)) >> 16;
}
__device__ inline float bf_lo(unsigned w) { return __uint_as_float(w << 16); }
__device__ inline float bf_hi(unsigned w) { return __uint_as_float(w & 0xffff0000u); }

__device__ inline unsigned short f2h(float f) {
    _Float16 h = (_Float16)f;
    return __builtin_bit_cast(unsigned short, h);
}
__device__ inline float h2f(unsigned u) {            // low 16 bits = f16
    _Float16 h = __builtin_bit_cast(_Float16, (unsigned short)(u & 0xffffu));
    return (float)h;
}
__device__ inline unsigned cvtpk(float lo, float hi) {   // 2xf32 -> packed bf16
    unsigned r;
    asm volatile("v_cvt_pk_bf16_f32 %0, %1, %2" : "=v"(r) : "v"(lo), "v"(hi));
    return r;
}
__device__ inline unsigned relu_pk(unsigned w) {     // relu on packed 2xbf16
    return w & ~(((w >> 15) & 0x10001u) * 0xFFFFu);
}
// fast softplus: max(v,0) + ln2 * log2(1 + 2^(-|v|*log2e)) — raw HW trans ops
__device__ inline float softplus_fast(float v) {
    float t = __builtin_amdgcn_exp2f(-fabsf(v) * 1.44269504088896f);
    return fmaxf(v, 0.f) + 0.693147180559945f * __builtin_amdgcn_logf(1.0f + t);
}

// ---------------- edge MLP: swapped MFMA, 2 groups per iteration -------------
__global__ __launch_bounds__(256) void k_edge_mlp(
    const float* __restrict__ edge_attr, const int* __restrict__ dst,
    const float* __restrict__ We1, const float* __restrict__ be1,
    const float* __restrict__ We2, const float* __restrict__ be2,
    float* __restrict__ ew, int* __restrict__ batom, int E, int NB)
{
    __shared__ int hist[256];
    const int tid = threadIdx.x;
    hist[tid] = 0;
    __syncthreads();

    const int lane = tid & 63;
    const int half = lane >> 5;
    const int lc   = lane & 31;
    const int wid  = blockIdx.x * 4 + (tid >> 6);
    const int nw   = gridDim.x * 4;
    const int G    = (E + 31) >> 5;

    // wave-invariant fragments
    bf16x8 bfr[4];    // A: We1^T block t
    bf16x8 abias[4];  // A: be1 column (k==0 only)
    bf16x8 bones;     // B: ones row (k==0 only)
    bf16x8 we2A[8];   // A: We2 16-slices
#pragma unroll
    for (int t = 0; t < 4; ++t) {
#pragma unroll
        for (int j = 0; j < 8; ++j) {
            int k = 4 * half + (j & 3) + 8 * (j >> 2);
            bfr[t][j]   = (short)f2bf(We1[k * HD + t * 32 + lc]);
            abias[t][j] = (half == 0 && j == 0) ? (short)f2bf(be1[t * 32 + lc]) : (short)0;
        }
    }
#pragma unroll
    for (int j = 0; j < 8; ++j)
        bones[j] = (half == 0 && j == 0) ? (short)0x3F80 : (short)0;
#pragma unroll
    for (int s = 0; s < 8; ++s)
#pragma unroll
        for (int j = 0; j < 8; ++j) {
            int k = 4 * half + (j & 3) + 8 * (j >> 2);
            we2A[s][j] = (short)f2bf(We2[s * 16 + k]);
        }
    const float be2v = be2[0];

    for (int g = wid * 2; g < G; g += nw * 2) {
        int g1 = g + 1;
        bool h1 = (g1 < G);
        int e0 = (g << 5) + lc;
        int e1 = h1 ? ((g1 << 5) + lc) : e0;
        int el0 = e0 < E ? e0 : E - 1;
        int el1 = e1 < E ? e1 : E - 1;
        bool own0 = (half == 0) && (e0 < E);
        bool own1 = h1 && (half == 0) && (e1 < E);
        if (own0) atomicAdd(&hist[((unsigned)dst[e0]) >> 8], 1);
        if (own1) atomicAdd(&hist[((unsigned)dst[e1]) >> 8], 1);

        const float4* r0 = reinterpret_cast<const float4*>(edge_attr + (size_t)el0 * EAD);
        const float4* r1 = reinterpret_cast<const float4*>(edge_attr + (size_t)el1 * EAD);
        float4 x00 = r0[half], x01 = r0[2 + half];
        float4 x10 = r1[half], x11 = r1[2 + half];
        union { uint2 u[2]; bf16x8 v; } af0, af1;
        af0.u[0] = make_uint2(cvtpk(x00.x, x00.y), cvtpk(x00.z, x00.w));
        af0.u[1] = make_uint2(cvtpk(x01.x, x01.y), cvtpk(x01.z, x01.w));
        af1.u[0] = make_uint2(cvtpk(x10.x, x10.y), cvtpk(x10.z, x10.w));
        af1.u[1] = make_uint2(cvtpk(x11.x, x11.y), cvtpk(x11.z, x11.w));

        f32x16 preA, preB;
#pragma unroll
        for (int i = 0; i < 16; ++i) { preA[i] = 0.f; preB[i] = 0.f; }
#pragma unroll
        for (int t = 0; t < 4; ++t) {
            f32x16 accA, accB;
#pragma unroll
            for (int i = 0; i < 16; ++i) { accA[i] = 0.f; accB[i] = 0.f; }
            accA = __builtin_amdgcn_mfma_f32_32x32x16_bf16(abias[t], bones, accA, 0, 0, 0);
            accB = __builtin_amdgcn_mfma_f32_32x32x16_bf16(abias[t], bones, accB, 0, 0, 0);
            accA = __builtin_amdgcn_mfma_f32_32x32x16_bf16(bfr[t], af0.v, accA, 0, 0, 0);
            accB = __builtin_amdgcn_mfma_f32_32x32x16_bf16(bfr[t], af1.v, accB, 0, 0, 0);
            union { uint2 u[2]; bf16x8 v; } ploA, phiA, ploB, phiB;
            ploA.u[0] = make_uint2(cvtpk(fmaxf(accA[0], 0.f),  fmaxf(accA[1], 0.f)),
                                   cvtpk(fmaxf(accA[2], 0.f),  fmaxf(accA[3], 0.f)));
            ploA.u[1] = make_uint2(cvtpk(fmaxf(accA[4], 0.f),  fmaxf(accA[5], 0.f)),
                                   cvtpk(fmaxf(accA[6], 0.f),  fmaxf(accA[7], 0.f)));
            phiA.u[0] = make_uint2(cvtpk(fmaxf(accA[8], 0.f),  fmaxf(accA[9], 0.f)),
                                   cvtpk(fmaxf(accA[10], 0.f), fmaxf(accA[11], 0.f)));
            phiA.u[1] = make_uint2(cvtpk(fmaxf(accA[12], 0.f), fmaxf(accA[13], 0.f)),
                                   cvtpk(fmaxf(accA[14], 0.f), fmaxf(accA[15], 0.f)));
            ploB.u[0] = make_uint2(cvtpk(fmaxf(accB[0], 0.f),  fmaxf(accB[1], 0.f)),
                                   cvtpk(fmaxf(accB[2], 0.f),  fmaxf(accB[3], 0.f)));
            ploB.u[1] = make_uint2(cvtpk(fmaxf(accB[4], 0.f),  fmaxf(accB[5], 0.f)),
                                   cvtpk(fmaxf(accB[6], 0.f),  fmaxf(accB[7], 0.f)));
            phiB.u[0] = make_uint2(cvtpk(fmaxf(accB[8], 0.f),  fmaxf(accB[9], 0.f)),
                                   cvtpk(fmaxf(accB[10], 0.f), fmaxf(accB[11], 0.f)));
            phiB.u[1] = make_uint2(cvtpk(fmaxf(accB[12], 0.f), fmaxf(accB[13], 0.f)),
                                   cvtpk(fmaxf(accB[14], 0.f), fmaxf(accB[15], 0.f)));
            preA = __builtin_amdgcn_mfma_f32_32x32x16_bf16(we2A[2*t],     ploA.v, preA, 0, 0, 0);
            preB = __builtin_amdgcn_mfma_f32_32x32x16_bf16(we2A[2*t],     ploB.v, preB, 0, 0, 0);
            preA = __builtin_amdgcn_mfma_f32_32x32x16_bf16(we2A[2*t + 1], phiA.v, preA, 0, 0, 0);
            preB = __builtin_amdgcn_mfma_f32_32x32x16_bf16(we2A[2*t + 1], phiB.v, preB, 0, 0, 0);
        }
        float v0 = preA[0] + be2v;
        float v1 = preB[0] + be2v;
        if (own0) ew[e0] = softplus_fast(v0);
        if (own1) ew[e1] = softplus_fast(v1);
    }
    __syncthreads();
    if (tid < NB && hist[tid]) atomicAdd(&batom[tid], hist[tid]);
}

// ---------------- scan bucket counts -> boff (exclusive), bcur copy -----------
__global__ __launch_bounds__(256) void k_bscan(
    const int* __restrict__ batom, int* __restrict__ boff,
    int* __restrict__ bcur, int NB)
{
    __shared__ int sh[256];
    int t = threadIdx.x;
    int v = (t < NB) ? batom[t] : 0;
    sh[t] = v;
    __syncthreads();
    for (int off = 1; off < 256; off <<= 1) {
        int add = (t >= off) ? sh[t - off] : 0;
        __syncthreads();
        sh[t] += add;
        __syncthreads();
    }
    if (t < NB) { boff[t] = sh[t] - v; bcur[t] = sh[t] - v; }
    if (t == NB - 1) boff[NB] = sh[t];
}

// ---------------- partition edges into coarse buckets ----------------
__global__ __launch_bounds__(256) void k_part(
    const int* __restrict__ src, const int* __restrict__ dst,
    const float* __restrict__ ew, int* __restrict__ bcur,
    uint2* __restrict__ bbuf, int E, int NB)
{
    __shared__ int hist[256];
    __shared__ int base[256];
    __shared__ int cur[256];
    int t = threadIdx.x;
    hist[t] = 0; cur[t] = 0;
    __syncthreads();
    int eb = blockIdx.x * PCHUNK;
#pragma unroll
    for (int k = 0; k < PCHUNK / 256; ++k) {
        int e = eb + k * 256 + t;
        if (e < E) atomicAdd(&hist[dst[e] >> 8], 1);
    }
    __syncthreads();
    if (t < NB && hist[t]) base[t] = atomicAdd(&bcur[t], hist[t]);
    __syncthreads();
#pragma unroll
    for (int k = 0; k < PCHUNK / 256; ++k) {
        int e = eb + k * 256 + t;
        if (e >= E) continue;
        int d = dst[e];
        int bkt = d >> 8;
        int pos = base[bkt] + atomicAdd(&cur[bkt], 1);
        bbuf[pos] = make_uint2(((unsigned)src[e] << 16) | f2h(ew[e]),
                               (unsigned)(d & 255));
    }
}

// ---------------- per-bucket counting sort: rp, dis, adj ----------------
__global__ __launch_bounds__(256) void k_bucket(
    const int* __restrict__ boff, const uint2* __restrict__ bbuf,
    int* __restrict__ rp, float* __restrict__ dis,
    unsigned* __restrict__ adj, int N, int E, int NB)
{
    __shared__ int   hcnt[256];
    __shared__ int   hexc[256];
    __shared__ int   cur[256];
    __shared__ float degs[256];
    int b = blockIdx.x;
    int t = threadIdx.x;
    hcnt[t] = 0; cur[t] = 0; degs[t] = 0.f;
    __syncthreads();
    int beg = boff[b], end = boff[b + 1];
    for (int i = beg + t; i < end; i += 256) {
        uint2 ent = bbuf[i];
        int dl = (int)ent.y;
        atomicAdd(&hcnt[dl], 1);
        atomicAdd(&degs[dl], h2f(ent.x));
    }
    __syncthreads();
    {
        int v = hcnt[t];
        hexc[t] = v;
        __syncthreads();
        for (int off = 1; off < 256; off <<= 1) {
            int add = (t >= off) ? hexc[t - off] : 0;
            __syncthreads();
            hexc[t] += add;
            __syncthreads();
        }
        hexc[t] -= v;
    }
    int n = (b << 8) + t;
    if (n < N) {
        rp[n]  = beg + hexc[t];
        dis[n] = rsqrtf(fmaxf(1.0f + degs[t], 1e-12f));
    }
    if (b == NB - 1 && t == 0) rp[N] = E;
    __syncthreads();
    for (int i = beg + t; i < end; i += 256) {
        uint2 ent = bbuf[i];
        int dl = (int)ent.y;
        int pos = beg + hexc[dl] + atomicAdd(&cur[dl], 1);
        adj[pos] = ent.x;
    }
}

// ------- MFMA GEMM: Ybf[row] = bf16( dis[row] * (relu?)X[row] @ W ) ----------
template <bool BF16IN, bool RELU>
__global__ __launch_bounds__(256) void k_gemm(
    const void* __restrict__ Xv, const float* __restrict__ W,
    const float* __restrict__ dis, unsigned short* __restrict__ Ybf, int N)
{
    __shared__ unsigned short Wt[128][132];
    int t = threadIdx.x;
#pragma unroll
    for (int i = 0; i < 64; ++i) {
        int e = i * 256 + t;
        int k = e >> 7, n = e & 127;
        Wt[n][k] = (unsigned short)f2bf(W[e]);
    }
    __syncthreads();

    const int lane = t & 63;
    const int half = lane >> 5;
    const int lc   = lane & 31;
    const int wid  = blockIdx.x * 4 + (t >> 6);
    const int nw   = gridDim.x * 4;
    const int T    = (N + 31) >> 5;

    for (int tile = wid; tile < T; tile += nw) {
        int rbase = tile << 5;
        int arow  = rbase + lc; if (arow >= N) arow = N - 1;

        f32x16 acc[4];
#pragma unroll
        for (int tb = 0; tb < 4; ++tb)
#pragma unroll
            for (int i = 0; i < 16; ++i) acc[tb][i] = 0.f;

#pragma unroll
        for (int kk = 0; kk < 8; ++kk) {
            union { uint2 u[2]; bf16x8 v; } af;
            if (BF16IN) {
                const unsigned short* Xb = (const unsigned short*)Xv;
                const unsigned short* rp = Xb + (size_t)arow * HD + kk * 16 + 4 * half;
                uint2 lo = *reinterpret_cast<const uint2*>(rp);
                uint2 hi = *reinterpret_cast<const uint2*>(rp + 8);
                if (RELU) {
                    lo.x = relu_pk(lo.x); lo.y = relu_pk(lo.y);
                    hi.x = relu_pk(hi.x); hi.y = relu_pk(hi.y);
                }
                af.u[0] = lo; af.u[1] = hi;
            } else {
                const float* Xf = (const float*)Xv;
                const float* rp = Xf + (size_t)arow * HD + kk * 16 + 4 * half;
                float4 lo = *reinterpret_cast<const float4*>(rp);
                float4 hi = *reinterpret_cast<const float4*>(rp + 8);
                af.u[0] = make_uint2(cvtpk(lo.x, lo.y), cvtpk(lo.z, lo.w));
                af.u[1] = make_uint2(cvtpk(hi.x, hi.y), cvtpk(hi.z, hi.w));
            }
#pragma unroll
            for (int tb = 0; tb < 4; ++tb) {
                const unsigned short* wp = &Wt[tb * 32 + lc][kk * 16 + 4 * half];
                union { uint2 u[2]; bf16x8 v; } bf_;
                bf_.u[0] = *reinterpret_cast<const uint2*>(wp);
                bf_.u[1] = *reinterpret_cast<const uint2*>(wp + 8);
                acc[tb] = __builtin_amdgcn_mfma_f32_32x32x16_bf16(af.v, bf_.v, acc[tb], 0, 0, 0);
            }
        }

        float disv = dis[arow];
#pragma unroll
        for (int r = 0; r < 16; ++r) {
            int rofs = (r & 3) + 8 * (r >> 2) + 4 * half;
            int grow = rbase + rofs;
            float d = __shfl(disv, rofs, 32);
            if (grow < N) {
#pragma unroll
                for (int tb = 0; tb < 4; ++tb)
                    Ybf[(size_t)grow * HD + tb * 32 + lc] =
                        (unsigned short)f2bf(acc[tb][r] * d);
            }
        }
    }
}

// --- gather: out[n] = bf16( b + dis[n] * (linbf[n] + sum ew*linbf[src]) ) -----
__global__ __launch_bounds__(256) void k_gather(
    const int* __restrict__ rp, const unsigned* __restrict__ adj,
    const unsigned* __restrict__ linbf, const float* __restrict__ dis,
    const float* __restrict__ b, unsigned short* __restrict__ out, int N)
{
    int n = blockIdx.x * 8 + (threadIdx.x >> 5);
    if (n >= N) return;
    int lane = threadIdx.x & 31;
    uint2 sw = *reinterpret_cast<const uint2*>(linbf + (size_t)n * (HD/2) + lane * 2);
    float4 acc;
    acc.x = bf_lo(sw.x); acc.y = bf_hi(sw.x);
    acc.z = bf_lo(sw.y); acc.w = bf_hi(sw.y);
    int beg = rp[n], end = rp[n + 1];
    for (int i0 = beg; i0 < end; i0 += 32) {
        int m = end - i0; if (m > 32) m = 32;
        unsigned a = 0;
        if (lane < m) a = adj[i0 + lane];
        int j = 0;
        for (; j + 16 <= m; j += 16) {
            unsigned ee[16]; uint2 vv[16];
#pragma unroll
            for (int q = 0; q < 16; ++q) ee[q] = __shfl(a, j + q, 32);
#pragma unroll
            for (int q = 0; q < 16; ++q)
                vv[q] = *reinterpret_cast<const uint2*>(linbf + (size_t)(ee[q] >> 16) * (HD/2) + lane * 2);
#pragma unroll
            for (int q = 0; q < 16; ++q) {
                float wq = h2f(ee[q]);
                acc.x = fmaf(wq, bf_lo(vv[q].x), acc.x);
                acc.y = fmaf(wq, bf_hi(vv[q].x), acc.y);
                acc.z = fmaf(wq, bf_lo(vv[q].y), acc.z);
                acc.w = fmaf(wq, bf_hi(vv[q].y), acc.w);
            }
        }
        for (; j + 8 <= m; j += 8) {
            unsigned ee[8]; uint2 vv[8];
#pragma unroll
            for (int q = 0; q < 8; ++q) ee[q] = __shfl(a, j + q, 32);
#pragma unroll
            for (int q = 0; q < 8; ++q)
                vv[q] = *reinterpret_cast<const uint2*>(linbf + (size_t)(ee[q] >> 16) * (HD/2) + lane * 2);
#pragma unroll
            for (int q = 0; q < 8; ++q) {
                float wq = h2f(ee[q]);
                acc.x = fmaf(wq, bf_lo(vv[q].x), acc.x);
                acc.y = fmaf(wq, bf_hi(vv[q].x), acc.y);
                acc.z = fmaf(wq, bf_lo(vv[q].y), acc.z);
                acc.w = fmaf(wq, bf_hi(vv[q].y), acc.w);
            }
        }
        for (; j < m; ++j) {
            unsigned e0 = __shfl(a, j, 32);
            uint2 v0 = *reinterpret_cast<const uint2*>(linbf + (size_t)(e0 >> 16) * (HD/2) + lane * 2);
            float w0 = h2f(e0);
            acc.x = fmaf(w0, bf_lo(v0.x), acc.x);
            acc.y = fmaf(w0, bf_hi(v0.x), acc.y);
            acc.z = fmaf(w0, bf_lo(v0.y), acc.z);
            acc.w = fmaf(w0, bf_hi(v0.y), acc.w);
        }
    }
    float dn = dis[n];
    float4 bv = reinterpret_cast<const float4*>(b)[lane];
    unsigned w0 = cvtpk(fmaf(dn, acc.x, bv.x), fmaf(dn, acc.y, bv.y));
    unsigned w1 = cvtpk(fmaf(dn, acc.z, bv.z), fmaf(dn, acc.w, bv.w));
    *reinterpret_cast<uint2*>(out + (size_t)n * HD + lane * 4) = make_uint2(w0, w1);
}

// ---------------- pool partials: 16 rows x 16 chunks per block-iter ----------
__global__ __launch_bounds__(256) void k_pool(
    const unsigned short* __restrict__ h, float* __restrict__ part, int N)
{
    __shared__ float sm[16][128];
    int t  = threadIdx.x;
    int cg = t & 15;              // uint4 chunk (8 bf16) within row
    int rs = t >> 4;              // row slot 0..15
    float acc[8];
#pragma unroll
    for (int i = 0; i < 8; ++i) acc[i] = 0.f;
    for (int r = blockIdx.x * 16 + rs; r < N; r += gridDim.x * 16) {
        uint4 v = *reinterpret_cast<const uint4*>(h + (size_t)r * HD + cg * 8);
        acc[0] += fmaxf(bf_lo(v.x), 0.f);
        acc[1] += fmaxf(bf_hi(v.x), 0.f);
        acc[2] += fmaxf(bf_lo(v.y), 0.f);
        acc[3] += fmaxf(bf_hi(v.y), 0.f);
        acc[4] += fmaxf(bf_lo(v.z), 0.f);
        acc[5] += fmaxf(bf_hi(v.z), 0.f);
        acc[6] += fmaxf(bf_lo(v.w), 0.f);
        acc[7] += fmaxf(bf_hi(v.w), 0.f);
    }
#pragma unroll
    for (int i = 0; i < 8; ++i) sm[rs][cg * 8 + i] = acc[i];
    __syncthreads();
    if (t < 128) {
        float s = 0.f;
#pragma unroll
        for (int k = 0; k < 16; ++k) s += sm[k][t];
        part[blockIdx.x * HD + t] = s;
    }
}

// ---- head: parallel partial-sum (8 chunks x 50) + wave-parallel GEMV --------
__global__ __launch_bounds__(1024) void k_head(
    const float* __restrict__ part, const float* __restrict__ Wh,
    const float* __restrict__ bh, float* __restrict__ out, float invN)
{
    __shared__ float smc[8][128];
    __shared__ float col[HD];
    int t = threadIdx.x;
    {
        int c  = t & 127;             // column
        int ch = t >> 7;              // chunk 0..7 (50 partials each)
        float s0 = 0.f, s1 = 0.f;
        int k0 = ch * 50;
#pragma unroll
        for (int k = 0; k < 50; k += 2) {
            s0 += part[(k0 + k)     * HD + c];
            s1 += part[(k0 + k + 1) * HD + c];
        }
        smc[ch][c] = s0 + s1;
    }
    __syncthreads();
    if (t < 128) {
        float s = 0.f;
#pragma unroll
        for (int k = 0; k < 8; ++k) s += smc[k][t];
        col[t] = s * invN;
    }
    __syncthreads();
    {
        int o = t >> 6;               // output index (only o<OUTD active)
        int l = t & 63;
        if (o < OUTD) {
            float acc = col[l] * Wh[l * OUTD + o]
                      + col[l + 64] * Wh[(l + 64) * OUTD + o];
#pragma unroll
            for (int off = 1; off < 64; off <<= 1)
                acc += __shfl_xor(acc, off, 64);
            if (l == 0) out[o] = acc + bh[o];
        }
    }
}

extern "C" void kernel_launch(void* const* d_in, const int* in_sizes, int n_in,
                              void* d_out, int out_size, void* d_ws, size_t ws_size,
                              hipStream_t stream)
{
    const float* x         = (const float*)d_in[0];
    const int*   ei        = (const int*)  d_in[1];
    const float* edge_attr = (const float*)d_in[2];
    const float* We1       = (const float*)d_in[3];
    const float* be1       = (const float*)d_in[4];
    const float* We2       = (const float*)d_in[5];
    const float* be2       = (const float*)d_in[6];
    const float* W1        = (const float*)d_in[7];
    const float* b1        = (const float*)d_in[8];
    const float* W2        = (const float*)d_in[9];
    const float* b2        = (const float*)d_in[10];
    const float* W3        = (const float*)d_in[11];
    const float* b3        = (const float*)d_in[12];
    const float* Wh        = (const float*)d_in[13];
    const float* bh        = (const float*)d_in[14];

    const int N = in_sizes[0] / HD;
    const int E = in_sizes[2] / EAD;
    const int NB = (N + 255) >> 8;
    const int* srcp = ei;
    const int* dstp = ei + E;

    // workspace partition
    char* w = (char*)d_ws;
    float*          ew   = (float*)w;          w += (size_t)E * sizeof(float);
    float*          dis  = (float*)w;          w += (size_t)N * sizeof(float);
    unsigned short* Bbf  = (unsigned short*)w; w += (size_t)N * HD * sizeof(unsigned short);
    unsigned*       Abf  = (unsigned*)w;       w += (size_t)N * (HD/2) * sizeof(unsigned);
    float*          part = (float*)w;          w += (size_t)PBLK * HD * sizeof(float);
    int*            rp   = (int*)w;            w += (size_t)(N + 2) * sizeof(int);
    int*            batom= (int*)w;            w += 256 * sizeof(int);
    int*            boff = (int*)w;            w += 260 * sizeof(int);
    int*            bcur = (int*)w;            w += 256 * sizeof(int);
    w = (char*)(((uintptr_t)w + 15) & ~(uintptr_t)15);
    uint2*          bbuf = (uint2*)w;          w += (size_t)E * sizeof(uint2);
    unsigned*       adj  = (unsigned*)w;       w += (size_t)E * sizeof(unsigned);

    const int gGe   = ceil_div(N, 8);
    const int gPart = ceil_div(E, PCHUNK);
    const int gGemm = 196;

    // batom = 0, then edge MLP (swapped MFMA, 2 groups/iter, fused count)
    hipMemsetAsync(batom, 0, 256 * sizeof(int), stream);
    k_edge_mlp<<<1024, 256, 0, stream>>>(edge_attr, dstp, We1, be1, We2, be2,
                                         ew, batom, E, NB);

    // CSR build: scan -> partition -> per-bucket sort
    k_bscan <<<1, 256, 0, stream>>>(batom, boff, bcur, NB);
    k_part  <<<gPart, 256, 0, stream>>>(srcp, dstp, ew, bcur, bbuf, E, NB);
    k_bucket<<<NB, 256, 0, stream>>>(boff, bbuf, rp, dis, adj, N, E, NB);

    // layer 1 (x is f32, no relu)
    k_gemm<false, false><<<gGemm, 256, 0, stream>>>(x, W1, dis, (unsigned short*)Abf, N);
    k_gather<<<gGe, 256, 0, stream>>>(rp, adj, Abf, dis, b1, Bbf, N);
    // layer 2 (bf16 input, relu)
    k_gemm<true, true><<<gGemm, 256, 0, stream>>>(Bbf, W2, dis, (unsigned short*)Abf, N);
    k_gather<<<gGe, 256, 0, stream>>>(rp, adj, Abf, dis, b2, Bbf, N);
    // layer 3
    k_gemm<true, true><<<gGemm, 256, 0, stream>>>(Bbf, W3, dis, (unsigned short*)Abf, N);
    k_gather<<<gGe, 256, 0, stream>>>(rp, adj, Abf, dis, b3, Bbf, N);

    // pool + head
    k_pool<<<PBLK, 256, 0, stream>>>(Bbf, part, N);
    k_head<<<1, 1024, 0, stream>>>(part, Wh, bh, (float*)d_out, 1.0f / (float)N);
}